// Round 11
// baseline (51.264 us; speedup 1.0000x reference)
//
#include <hip/hip_runtime.h>

// FastGuidedFilter, two-kernel split to minimize in-block prologue.
// Kernel A (ab_kernel): one block per (lowres row, channel). Computes A,b via
//   staged 5-row window stats, writes interleaved f2{A,b} plane to d_ws.
//   Total traffic ~38 MB -> ~5 us.
// Kernel B (fgf_stream): one block per (16 hr rows, channel). Prologue is ONE
//   coalesced 12 KB LDS load of 6 A/b rows + 1 barrier (~0.3 us), then the
//   proven R9 streaming loop (shift-window y-combine, depth-8 ring, plain
//   stores). LDS 12.3 KB -> 8 blocks/CU (wave-capped 32 waves/CU).

typedef float f4 __attribute__((ext_vector_type(4)));
typedef float f2 __attribute__((ext_vector_type(2)));

constexpr int H_LR = 256, W_LR = 256;
constexpr int H_HR = 1024, W_HR = 1024;
constexpr int NC   = 24;       // 8 * 3
constexpr int RAD  = 2;        // kernel_size 5
constexpr int RPB  = 16;       // highres rows per block (kernel B)
constexpr int NAB  = 6;        // A/b rows a 16-row group can touch
constexpr int CS_W = W_LR + 4; // zero-padded col-sum width
constexpr int PD   = 8;        // streaming prefetch depth

// ---------------- Kernel A: A,b planes ----------------
__global__ void __launch_bounds__(256) ab_kernel(const float* __restrict__ xlr,
                                                 const float* __restrict__ ylr,
                                                 f2* __restrict__ wsab) {
    __shared__ float sx[5][W_LR];
    __shared__ float sy[5][W_LR];
    __shared__ __align__(16) float cs[CS_W][4];

    const int r = blockIdx.x;            // lowres row
    const int c = blockIdx.y;            // channel
    const int t = (int)threadIdx.x;
    const int lrbase = c * (H_LR * W_LR);

    // stage rows r-2..r+2 of x,y (zero outside image): 640 f4 over 256 thr
    for (int idx = t; idx < 640; idx += 256) {
        const bool isx = idx < 320;
        const int  id2 = isx ? idx : idx - 320;
        const int  lr  = id2 >> 6, q = id2 & 63;
        const int  gr  = r - RAD + lr;
        const float* src = isx ? xlr : ylr;
        f4 v = {0.f, 0.f, 0.f, 0.f};
        if (gr >= 0 && gr < H_LR) v = *(const f4*)(src + lrbase + gr * W_LR + q * 4);
        if (isx) *(f4*)&sx[lr][q * 4] = v;
        else     *(f4*)&sy[lr][q * 4] = v;
    }
    __syncthreads();

    // vertical 5-tap column sums (zeros outside contribute nothing)
    float s0 = 0.f, s1 = 0.f, s2 = 0.f, s3 = 0.f;
    #pragma unroll
    for (int l = 0; l < 5; ++l) {
        const float vx = sx[l][t];
        const float vy = sy[l][t];
        s0 += vx; s1 += vy; s2 += vx * vy; s3 += vx * vx;
    }
    *(f4*)&cs[t + 2][0] = f4{s0, s1, s2, s3};
    if (t < 2) {
        const f4 z = {0.f, 0.f, 0.f, 0.f};
        *(f4*)&cs[t][0] = z;
        *(f4*)&cs[t + W_LR + 2][0] = z;
    }
    __syncthreads();

    // horizontal 5-tap + stats
    f4 s = {0.f, 0.f, 0.f, 0.f};
    #pragma unroll
    for (int d = 0; d < 5; ++d) s += *(const f4*)&cs[t + d][0];
    const int  hcnt = min(t + RAD, W_LR - 1) - max(t - RAD, 0) + 1;
    const int  vcnt = min(r + RAD, H_LR - 1) - max(r - RAD, 0) + 1;
    const float inv = 1.0f / (float)(vcnt * hcnt);
    const float mx  = s.x * inv;
    const float my  = s.y * inv;
    const float cov = s.z * inv - mx * my;
    const float var = s.w * inv - mx * mx;
    const float a   = cov / (var + 1e-8f);
    wsab[(c << 16) | (r << 8) | t] = f2{a, my - a * mx};
}

// ---------------- Kernel B: streaming upsample + apply ----------------
__global__ void __launch_bounds__(256) fgf_stream(const f2* __restrict__ wsab,
                                                  const float* __restrict__ xhr,
                                                  float* __restrict__ out) {
    __shared__ __align__(16) f2 ab2[NAB][W_LR];    // 12 KB

    const int c  = blockIdx.y;
    const int i0 = blockIdx.x * RPB;
    const int t  = (int)threadIdx.x;
    const float scale = (float)(H_LR - 1) / (float)(H_HR - 1);   // 255/1023

    const int y0min = (int)((float)i0 * scale);                  // floor, >= 0

    // ---- prologue: load 6 A/b rows (clamped) -- 768 f4, 3 rounds, 1 barrier
    {
        f4* dst = (f4*)&ab2[0][0];
        #pragma unroll
        for (int rnd = 0; rnd < 3; ++rnd) {
            const int idx = rnd * 256 + t;         // 0..767
            const int row = idx >> 7;              // 0..5 (128 f4 per row)
            const int q   = idx & 127;
            const int gr  = min(y0min + row, H_LR - 1);
            dst[idx] = *(const f4*)((const float*)(wsab + ((c << 16) | (gr << 8))) + q * 4);
        }
    }
    __syncthreads();

    // ---- A3: columns {t-1, t, t+1} (clamped), all 6 rows
    const int cl = max(t - 1, 0), ch = min(t + 1, W_LR - 1);
    f2 A3[NAB][3];
    #pragma unroll
    for (int rr = 0; rr < NAB; ++rr) {
        A3[rr][0] = ab2[rr][cl];
        A3[rr][1] = ab2[rr][t];
        A3[rr][2] = ab2[rr][ch];
    }

    // x-interp selectors per m (x0 in {t-1,t}, x1 in {t,t+1})
    float wxv[4], wx0v[4];
    bool  lo[4], hi[4];
    #pragma unroll
    for (int m = 0; m < 4; ++m) {
        const int   j  = t * 4 + m;
        const float fx = (float)j * scale;
        const int   x0 = (int)fx;
        wxv[m]  = fx - (float)x0;
        wx0v[m] = 1.f - wxv[m];
        lo[m]   = (x0 < t);
        hi[m]   = (x0 == t) && (t < W_LR - 1);
    }

    // ---- streaming: depth-8 ring, shift-window y-combine, plain stores
    const size_t hrbase = ((size_t)c << 20) + (size_t)i0 * W_HR + (size_t)t * 4;
    const float* srcp = xhr + hrbase;
    float*       dstp = out + hrbase;

    f4 buf[PD];
    #pragma unroll
    for (int k = 0; k < PD; ++k)
        buf[k] = *(const f4*)(srcp + (size_t)k * W_HR);
    asm volatile("" ::: "memory");

    f2 c0l = A3[0][0], c0c = A3[0][1], c0r = A3[0][2];
    f2 c1l = A3[1][0], c1c = A3[1][1], c1r = A3[1][2];
    int cur = 0;

    #pragma unroll
    for (int k = 0; k < RPB; ++k) {
        const f4 xvk = buf[k & (PD - 1)];

        const float fy  = (float)(i0 + k) * scale;
        const int   yy0 = (int)fy;
        const int   l0  = yy0 - y0min;             // block-uniform, 0..4
        if (l0 != cur) {                           // uniform branch, +1 steps
            c0l = c1l; c0c = c1c; c0r = c1r;
            const int nxt = (l0 + 1 < NAB) ? l0 + 1 : NAB - 1;
            switch (nxt) {
                case 2:  c1l = A3[2][0]; c1c = A3[2][1]; c1r = A3[2][2]; break;
                case 3:  c1l = A3[3][0]; c1c = A3[3][1]; c1r = A3[3][2]; break;
                case 4:  c1l = A3[4][0]; c1c = A3[4][1]; c1r = A3[4][2]; break;
                default: c1l = A3[5][0]; c1c = A3[5][1]; c1r = A3[5][2]; break;
            }
            cur = l0;
        }
        const float wyk = (yy0 < H_LR - 1) ? (fy - (float)yy0) : 0.f;
        const float wy0 = 1.f - wyk;
        const f2 r0 = wy0 * c0l + wyk * c1l;
        const f2 r1 = wy0 * c0c + wyk * c1c;
        const f2 r2 = wy0 * c0r + wyk * c1r;

        f4 ov;
        #pragma unroll
        for (int m = 0; m < 4; ++m) {
            const f2 pl  = lo[m] ? r0 : r1;
            const f2 ph  = hi[m] ? r2 : r1;
            const f2 abv = wx0v[m] * pl + wxv[m] * ph;
            ov[m] = abv.x * xvk[m] + abv.y;
        }
        *(f4*)(dstp + (size_t)k * W_HR) = ov;

        if (k + PD < RPB) {
            buf[k & (PD - 1)] = *(const f4*)(srcp + (size_t)(k + PD) * W_HR);
            asm volatile("" ::: "memory");
        }
    }
}

extern "C" void kernel_launch(void* const* d_in, const int* in_sizes, int n_in,
                              void* d_out, int out_size, void* d_ws, size_t ws_size,
                              hipStream_t stream) {
    const float* x_lr = (const float*)d_in[0];  // input_lowres  [8,3,256,256]
    const float* y_lr = (const float*)d_in[1];  // guide_lowres  [8,3,256,256]
    const float* x_hr = (const float*)d_in[2];  // input_highres [8,3,1024,1024]
    float* out = (float*)d_out;
    f2*    wsab = (f2*)d_ws;                    // [24][256][256] f2 = 12.6 MB

    dim3 gA(H_LR, NC, 1);                       // 256 x 24 = 6144 blocks
    ab_kernel<<<gA, 256, 0, stream>>>(x_lr, y_lr, wsab);

    dim3 gB(H_HR / RPB, NC, 1);                 // 64 x 24 = 1536 blocks
    fgf_stream<<<gB, 256, 0, stream>>>(wsab, x_hr, out);
}

// Round 12
// 40.873 us; speedup vs baseline: 1.2542x; 1.2542x over previous
//
#include <hip/hip_runtime.h>

// FastGuidedFilter, fully fused, 16 highres rows per block (1536 blocks = 6/CU).
// CHAMPION (round 9, 41.1 us): phases 1-4 compute A,b on the lowres grid in
// LDS (aliased regions, 5 barriers); phase 5 streams x_hr -> out with a
// depth-8 prefetch ring, shift-window y-combine, packed f2 x-interp, plain
// cached stores. All levers beyond this were tested R4-R11 and are neutral:
// traffic is minimal (~160 MB HBM after L3), conflicts 0, VALU <25%, and the
// streaming rate is the practical mixed R/W HBM ceiling (~76% of copy ubench).

typedef float f4 __attribute__((ext_vector_type(4)));
typedef float f2 __attribute__((ext_vector_type(2)));

constexpr int H_LR = 256, W_LR = 256;
constexpr int H_HR = 1024, W_HR = 1024;
constexpr int NC   = 24;       // 8 * 3
constexpr int RAD  = 2;        // kernel_size 5
constexpr int RPB  = 16;       // highres rows per block
constexpr int NAB  = 6;        // A/b rows a 16-row group can touch
constexpr int NST  = 10;       // staged lowres rows (NAB + 2*RAD)
constexpr int CS_W = W_LR + 4; // zero-padded col-sum width
constexpr int PD   = 8;        // phase-5 prefetch depth

constexpr int LDS_BYTES = NAB * CS_W * 4 * 4;  // 24960 (largest aliased region)

__global__ void __launch_bounds__(256) fgf_fused(const float* __restrict__ xlr,
                                                 const float* __restrict__ ylr,
                                                 const float* __restrict__ xhr,
                                                 float* __restrict__ out) {
    __shared__ __align__(16) char lds[LDS_BYTES];
    auto sx = reinterpret_cast<float(*)[W_LR]>(lds);                   // [10][256]
    auto sy = reinterpret_cast<float(*)[W_LR]>(lds + NST * W_LR * 4);  // [10][256]
    auto cs = reinterpret_cast<float(*)[CS_W][4]>(lds);                // [6][260][4]
    auto ab = reinterpret_cast<f2(*)[W_LR]>(lds);                      // [6][256] f2

    const int c  = blockIdx.y;
    const int i0 = blockIdx.x * RPB;
    const int t  = (int)threadIdx.x;
    const float scale = (float)(H_LR - 1) / (float)(H_HR - 1);         // 255/1023

    const int y0min = (int)((float)i0 * scale);                        // floor, >= 0

    // ---- 1. stage lowres rows y0min-2 .. y0min+7 (both planes, 5 rounds)
    const int lrbase = c * (H_LR * W_LR);
    f4  stv[5];
    int soff[5];
    #pragma unroll
    for (int r = 0; r < 5; ++r) {
        const int  idx = r * 256 + t;              // 0..1279
        const bool isx = idx < NST * 64;           // first 640 = x plane
        const int  id2 = isx ? idx : idx - NST * 64;
        const int  lr  = id2 >> 6, q = id2 & 63;
        const int  gr  = y0min - 2 + lr;
        const float* src = isx ? xlr : ylr;
        f4 v = {0.f, 0.f, 0.f, 0.f};
        if (gr >= 0 && gr < H_LR) v = *(const f4*)(src + lrbase + gr * W_LR + q * 4);
        stv[r]  = v;
        soff[r] = (isx ? 0 : NST * W_LR) + lr * W_LR + q * 4;  // float offset
    }
    {
        float* base = (float*)lds;
        #pragma unroll
        for (int r = 0; r < 5; ++r) *(f4*)(base + soff[r]) = stv[r];
    }
    __syncthreads();                               // (1)

    // ---- 2. vertical rolling window sums, column t
    float vx[NST], vy[NST];
    #pragma unroll
    for (int l = 0; l < NST; ++l) { vx[l] = sx[l][t]; vy[l] = sy[l][t]; }
    __syncthreads();                               // (2) staging reads done; cs aliases

    float pxy[NST], pxx[NST];
    #pragma unroll
    for (int l = 0; l < NST; ++l) { pxy[l] = vx[l] * vy[l]; pxx[l] = vx[l] * vx[l]; }
    float s0 = 0.f, s1 = 0.f, s2 = 0.f, s3 = 0.f;
    #pragma unroll
    for (int l = 0; l < 5; ++l) { s0 += vx[l]; s1 += vy[l]; s2 += pxy[l]; s3 += pxx[l]; }
    #pragma unroll
    for (int rr = 0; rr < NAB; ++rr) {
        const f4 v = {s0, s1, s2, s3};
        *(f4*)&cs[rr][t + 2][0] = v;
        if (rr + 1 < NAB) {
            s0 += vx[rr + 5] - vx[rr];
            s1 += vy[rr + 5] - vy[rr];
            s2 += pxy[rr + 5] - pxy[rr];
            s3 += pxx[rr + 5] - pxx[rr];
        }
    }
    if (t < 2) {                                   // zero-pad columns
        const f4 z = {0.f, 0.f, 0.f, 0.f};
        #pragma unroll
        for (int rr = 0; rr < NAB; ++rr) {
            *(f4*)&cs[rr][t][0] = z;
            *(f4*)&cs[rr][t + W_LR + 2][0] = z;
        }
    }
    __syncthreads();                               // (3)

    // ---- 3. horizontal 5-tap + stats -> registers
    const int hcnt = min(t + RAD, W_LR - 1) - max(t - RAD, 0) + 1;
    float aa[NAB], bb[NAB];
    #pragma unroll
    for (int rr = 0; rr < NAB; ++rr) {
        f4 s = {0.f, 0.f, 0.f, 0.f};
        #pragma unroll
        for (int d = 0; d < 5; ++d) s += *(const f4*)&cs[rr][t + d][0];
        const int r  = y0min + rr;                 // may exceed 255: harmless (cnt>=2)
        const int v0 = max(r - RAD, 0), v1 = min(r + RAD, H_LR - 1);
        const float inv = 1.0f / (float)((v1 - v0 + 1) * hcnt);
        const float mx  = s.x * inv;
        const float my  = s.y * inv;
        const float cov = s.z * inv - mx * my;
        const float var = s.w * inv - mx * mx;
        aa[rr] = cov / (var + 1e-8f);
        bb[rr] = my - aa[rr] * mx;
    }
    __syncthreads();                               // (4) cs reads done; ab aliases

    #pragma unroll
    for (int rr = 0; rr < NAB; ++rr) ab[rr][t] = f2{aa[rr], bb[rr]};
    __syncthreads();                               // (5)

    // ---- 4. read back only columns {t-1, t, t+1} (clamped), all 6 rows
    const int cl = max(t - 1, 0), ch = min(t + 1, W_LR - 1);
    f2 A3[NAB][3];
    #pragma unroll
    for (int rr = 0; rr < NAB; ++rr) {
        A3[rr][0] = ab[rr][cl];
        A3[rr][1] = ab[rr][t];
        A3[rr][2] = ab[rr][ch];
    }

    // x-interp selectors per m (x0 in {t-1,t}, x1 in {t,t+1})
    float wxv[4], wx0v[4];
    bool  lo[4], hi[4];
    #pragma unroll
    for (int m = 0; m < 4; ++m) {
        const int   j  = t * 4 + m;
        const float fx = (float)j * scale;
        const int   x0 = (int)fx;
        wxv[m]  = fx - (float)x0;
        wx0v[m] = 1.f - wxv[m];
        lo[m]   = (x0 < t);
        hi[m]   = (x0 == t) && (t < W_LR - 1);
    }

    // ---- 5. depth-8 ring, plain stores, shift-window y-combine
    const size_t hrbase = ((size_t)c << 20) + (size_t)i0 * W_HR + (size_t)t * 4;
    const float* srcp = xhr + hrbase;
    float*       dstp = out + hrbase;

    f4 buf[PD];
    #pragma unroll
    for (int k = 0; k < PD; ++k)
        buf[k] = *(const f4*)(srcp + (size_t)k * W_HR);
    asm volatile("" ::: "memory");                 // pin the 8 loads in flight

    f2 c0l = A3[0][0], c0c = A3[0][1], c0r = A3[0][2];
    f2 c1l = A3[1][0], c1c = A3[1][1], c1r = A3[1][2];
    int cur = 0;

    #pragma unroll
    for (int k = 0; k < RPB; ++k) {                // fully unrolled
        const f4 xvk = buf[k & (PD - 1)];

        const float fy  = (float)(i0 + k) * scale;
        const int   yy0 = (int)fy;
        const int   l0  = yy0 - y0min;             // 0..4, block-uniform
        if (l0 != cur) {                           // uniform branch, +1 steps
            c0l = c1l; c0c = c1c; c0r = c1r;
            const int nxt = (l0 + 1 < NAB) ? l0 + 1 : NAB - 1;
            switch (nxt) {
                case 2:  c1l = A3[2][0]; c1c = A3[2][1]; c1r = A3[2][2]; break;
                case 3:  c1l = A3[3][0]; c1c = A3[3][1]; c1r = A3[3][2]; break;
                case 4:  c1l = A3[4][0]; c1c = A3[4][1]; c1r = A3[4][2]; break;
                default: c1l = A3[5][0]; c1c = A3[5][1]; c1r = A3[5][2]; break;
            }
            cur = l0;
        }
        // clamp row: when yy0==255, reference's y1==y0 -> weight collapses
        const float wyk = (yy0 < H_LR - 1) ? (fy - (float)yy0) : 0.f;
        const float wy0 = 1.f - wyk;
        const f2 r0 = wy0 * c0l + wyk * c1l;
        const f2 r1 = wy0 * c0c + wyk * c1c;
        const f2 r2 = wy0 * c0r + wyk * c1r;

        f4 ov;
        #pragma unroll
        for (int m = 0; m < 4; ++m) {
            const f2 pl  = lo[m] ? r0 : r1;
            const f2 ph  = hi[m] ? r2 : r1;
            const f2 abv = wx0v[m] * pl + wxv[m] * ph;   // packed (a,b)
            ov[m] = abv.x * xvk[m] + abv.y;
        }
        *(f4*)(dstp + (size_t)k * W_HR) = ov;      // cached store (L3-resident)

        if (k + PD < RPB) {
            buf[k & (PD - 1)] = *(const f4*)(srcp + (size_t)(k + PD) * W_HR);
            asm volatile("" ::: "memory");         // keep ring depth real
        }
    }
}

extern "C" void kernel_launch(void* const* d_in, const int* in_sizes, int n_in,
                              void* d_out, int out_size, void* d_ws, size_t ws_size,
                              hipStream_t stream) {
    const float* x_lr = (const float*)d_in[0];  // input_lowres  [8,3,256,256]
    const float* y_lr = (const float*)d_in[1];  // guide_lowres  [8,3,256,256]
    const float* x_hr = (const float*)d_in[2];  // input_highres [8,3,1024,1024]
    float* out = (float*)d_out;

    dim3 grid(H_HR / RPB, NC, 1);               // 64 x 24 = 1536 blocks (6/CU)
    fgf_fused<<<grid, 256, 0, stream>>>(x_lr, y_lr, x_hr, out);
}